// Round 3
// baseline (1316.519 us; speedup 1.0000x reference)
//
#include <hip/hip_runtime.h>
#include <stdint.h>

// Problem constants (from reference)
#define B_   32
#define T_   63      // S-1
#define U_   512
#define E_   256
#define V_   32000
#define L_   64
#define FU_  2048    // 4U
#define KFC_ 1024    // 2U
#define MROW_ 2016   // B*T

// FC fold geometry
#define NFCX_ 250    // 32000/128 col panels
#define NFCY_ 16     // 2048/128 row panels
#define CCNT_BASE 1024   // ccnt[t] lives at hcnt[CCNT_BASE + t*16]
// flags in Afc's unused rows 2016..2047 (u32 view): wfcTrdy[cx] at [cx*16],
// fcdone[ry] at [4096 + ry*16]; zeroed (8192 u32) by k_prep.
#define AFC_FLAG_U32 (2016 * 512)

typedef float f32x4 __attribute__((ext_vector_type(4)));
typedef float f32x2 __attribute__((ext_vector_type(2)));
typedef __bf16 bf16x8 __attribute__((ext_vector_type(8)));

__device__ __forceinline__ unsigned short f2bf(float f) {
  union { float f; unsigned u; } v; v.f = f;
  unsigned u = v.u;
  u += 0x7FFFu + ((u >> 16) & 1u);   // round-to-nearest-even
  return (unsigned short)(u >> 16);
}
__device__ __forceinline__ float bf2f(unsigned short h) {
  union { unsigned u; float f; } v; v.u = ((unsigned)h) << 16;
  return v.f;
}
__device__ __forceinline__ float fast_sigmoid(float x) {
  return 1.f / (1.f + __expf(-x));
}
__device__ __forceinline__ float fast_tanh(float x) {
  float e = __expf(2.f * x);          // x>>0: e=inf -> 1; x<<0: e=0 -> -1
  return 1.f - 2.f / (e + 1.f);
}

// ---------------------------------------------------------------- k_prep
// Precompute (W_fc transpose folded into k_rec):
//   [0,512)      fragWh : W_h -> MFMA B-fragment layout (bf16)
//   [512,1016)   zx     : Zx[t][b] = bf16(emb[target] @ W_x + b_lstm)
//   [1016,1272)  encproj: enc_out @ Wa (f32)
//   [1272,1528)  encT   : enc_out transposed to [b][u][l] bf16
//   [1528,1536)  zero   : hcnt + ccnt + Afc-flag region + row_sums
__global__ __launch_bounds__(256) void k_prep(const int* __restrict__ target,
    const float* __restrict__ emb, const float* __restrict__ W_x,
    const float* __restrict__ b_lstm, const float* __restrict__ enc_out,
    const float* __restrict__ Wa, const float* __restrict__ W_h,
    unsigned short* __restrict__ fragWh, unsigned short* __restrict__ Zx,
    float* __restrict__ enc_proj, unsigned short* __restrict__ encT,
    unsigned int* __restrict__ hcnt, float* __restrict__ row_sums,
    unsigned int* __restrict__ AfcFlags) {
  __shared__ __align__(16) char smem[32768];
  const int bx = blockIdx.x;
  const int tid = threadIdx.x;

  if (bx < 512) {
    // ---- fragWh[ct][kc][lane][j] = bf16(W_h[kc*32+(lane>>4)*8+j][ct*16+(lane&15)])
    int idx = bx * 256 + tid;   // 0..131071
    int lane = idx & 63;
    int kc   = (idx >> 6) & 15;
    int ct   = idx >> 10;
    int quad = lane >> 4, l15 = lane & 15;
    int col = ct * 16 + l15;
    unsigned short* dst = fragWh + (size_t)idx * 8;
#pragma unroll
    for (int j = 0; j < 8; ++j) {
      int k = kc * 32 + quad * 8 + j;
      dst[j] = f2bf(W_h[(size_t)k * FU_ + col]);
    }
  } else if (bx < 1016) {
    // ---- Zx
    float* x_lds = (float*)smem;          // 32 KB
    int r = bx - 512;                     // 0..503
    int t = r % 63, cc = r / 63;
    for (int i = tid; i < B_ * E_; i += 256) {
      int b = i >> 8, e = i & 255;
      x_lds[i] = emb[(size_t)target[b * 64 + t] * E_ + e];
    }
    __syncthreads();
    int col = cc * 256 + tid;
    float acc[B_];
#pragma unroll
    for (int b = 0; b < B_; ++b) acc[b] = 0.f;
    for (int e4 = 0; e4 < E_ / 4; ++e4) {
      float w0 = W_x[(size_t)(4 * e4 + 0) * FU_ + col];
      float w1 = W_x[(size_t)(4 * e4 + 1) * FU_ + col];
      float w2 = W_x[(size_t)(4 * e4 + 2) * FU_ + col];
      float w3 = W_x[(size_t)(4 * e4 + 3) * FU_ + col];
#pragma unroll
      for (int b = 0; b < B_; ++b) {
        f32x4 xv = *(const f32x4*)&x_lds[b * E_ + 4 * e4];
        acc[b] += xv[0] * w0 + xv[1] * w1 + xv[2] * w2 + xv[3] * w3;
      }
    }
    float bias = b_lstm[col];
#pragma unroll
    for (int b = 0; b < B_; ++b)
      Zx[((size_t)(t * B_ + b)) * FU_ + col] = f2bf(acc[b] + bias);
  } else if (bx < 1272) {
    // ---- enc_proj
    float* e_lds = (float*)smem;          // 32 KB
    int r = bx - 1016;                    // 0..255
    int rc = r & 127, cc = r >> 7;
    int row0 = rc * 16;
    for (int i = tid; i < 16 * U_; i += 256)
      e_lds[i] = enc_out[(size_t)(row0 + (i >> 9)) * U_ + (i & 511)];
    __syncthreads();
    int col = cc * 256 + tid;
    float acc[16];
#pragma unroll
    for (int q = 0; q < 16; ++q) acc[q] = 0.f;
    for (int k4 = 0; k4 < U_ / 4; ++k4) {
      float w0 = Wa[(size_t)(4 * k4 + 0) * U_ + col];
      float w1 = Wa[(size_t)(4 * k4 + 1) * U_ + col];
      float w2 = Wa[(size_t)(4 * k4 + 2) * U_ + col];
      float w3 = Wa[(size_t)(4 * k4 + 3) * U_ + col];
#pragma unroll
      for (int q = 0; q < 16; ++q) {
        f32x4 xv = *(const f32x4*)&e_lds[q * U_ + 4 * k4];
        acc[q] += xv[0] * w0 + xv[1] * w1 + xv[2] * w2 + xv[3] * w3;
      }
    }
#pragma unroll
    for (int q = 0; q < 16; ++q)
      enc_proj[(size_t)(row0 + q) * U_ + col] = acc[q];
  } else if (bx < 1528) {
    // ---- encT[b][u][l] = bf16(enc_out[b][l][u])
    float (*tile)[65] = (float(*)[65])smem;   // 64x65 f32 = 16.6 KB
    int r = bx - 1272;                        // 0..255
    int b = r & 31, uc = r >> 5;
#pragma unroll
    for (int i = 0; i < 16; ++i) {
      int idx = i * 256 + tid;            // 0..4095
      int l = idx >> 6, u = idx & 63;
      tile[l][u] = enc_out[((size_t)b * L_ + l) * U_ + uc * 64 + u];
    }
    __syncthreads();
#pragma unroll
    for (int i = 0; i < 16; ++i) {
      int idx = i * 256 + tid;
      int u = idx >> 6, l = idx & 63;
      encT[((size_t)b * U_ + uc * 64 + u) * L_ + l] = f2bf(tile[l][u]);
    }
  } else {
    // ---- zero flags (hcnt + ccnt) + Afc flag region + row_sums
    int i = (bx - 1528) * 256 + tid;      // 0..2047
    hcnt[i] = 0u;
    if (i < MROW_) row_sums[i] = 0.f;
    AfcFlags[i * 4 + 0] = 0u;
    AfcFlags[i * 4 + 1] = 0u;
    AfcFlags[i * 4 + 2] = 0u;
    AfcFlags[i * 4 + 3] = 0u;
  }
}

// ---------------------------------------------------------------- k_rec
// 4064 blocks x 256 threads, single launch.
//   blocks 0..31    (g): LSTM producers — u-slice [g*16, g*16+16) of all 4 gates.
//   blocks 32..63   (b): attention consumers — batch element b, all 63 steps.
//   blocks 64..4063   : folded FC GEMM tiles, flag-gated on consumer progress.
//     ry==0 blocks additionally transpose their W_fc B-panel first (hidden
//     under early recurrence steps); cx<128 blocks additionally normalize one
//     output row after fcdone[ry]==250 (folds the old k_lsm).
// All cross-block data goes through LLC with relaxed agent-scope atomics;
// __syncthreads() drains vmcnt(0) before each flag publish (proven pattern).
// Deadlock-freedom: in-order dispatch; every wait targets either permanently
// resident blocks 0..63 or later blocks of the SAME panel (acyclic).
__global__ __launch_bounds__(256, 1) void k_rec(const float* __restrict__ enc_h0,
    const float* __restrict__ enc_c0,
    const float* __restrict__ enc_proj, const unsigned short* __restrict__ Zx,
    const unsigned short* __restrict__ fragWh, const unsigned short* __restrict__ encT,
    unsigned int* hseq32,                  // 64 steps x (B_*U_/2) u32 (bf16 pairs)
    unsigned short* __restrict__ Afc,      // 2048 x 1024 bf16 [ctx | h] + flag rows
    unsigned int* hcnt,                    // flags: hcnt[t*16]; ccnt at [1024+t*16]
    unsigned short* __restrict__ WfcT, const float* __restrict__ b_fc,
    float* __restrict__ out, float* __restrict__ row_sums,
    const float* __restrict__ W_fc) {
  // LDS union: producer 44160 B | consumer 3328 B | fc 16900+ B
  __shared__ __align__(16) char smem[44160];

  const int tid = threadIdx.x;
  unsigned long long* hseq64 = (unsigned long long*)hseq32;
  unsigned int* AfcFlags = (unsigned int*)Afc + AFC_FLAG_U32;

  if (blockIdx.x < 32) {
    // ---------------- producer ----------------
    unsigned short* h_lds = (unsigned short*)smem;        // 32 x 520 u16 = 33280 B
    float* z_lds = (float*)(smem + 33280);                // 32 x 68 f32 = 8704 B
    float* c_lds = (float*)(smem + 41984);                // 32 x 17 f32 = 2176 B

    const int g = blockIdx.x;
    const int w = tid >> 6;
    const int lane = tid & 63;
    const int quad = lane >> 4;
    const int l15 = lane & 15;
    const int b = tid >> 3;      // gate-phase mapping: 32 b x 8 j
    const int j = tid & 7;       // u = g*16 + 2j, 2j+1

    // hoist step-invariant W_h B-fragments into registers (64 VGPRs)
    const unsigned short* bbase = fragWh + ((size_t)(w * 32 + g) * 16) * 64 * 8;
    bf16x8 bfr[16];
#pragma unroll
    for (int kc = 0; kc < 16; ++kc)
      bfr[kc] = *(const bf16x8*)(bbase + (size_t)(kc * 64 + lane) * 8);

    // latency-critical waves: preferential issue vs co-resident FC waves
    __builtin_amdgcn_s_setprio(1);

    // init: c slice -> LDS (fp32, persistent); h0 slice -> hseq[0]
    {
      int u = g * 16 + 2 * j;
      float h0a = enc_h0[(size_t)b * U_ + u];
      float h0b = enc_h0[(size_t)b * U_ + u + 1];
      unsigned pack = (unsigned)f2bf(h0a) | ((unsigned)f2bf(h0b) << 16);
      __hip_atomic_store(&hseq32[b * 256 + g * 8 + j], pack,
                         __ATOMIC_RELAXED, __HIP_MEMORY_SCOPE_AGENT);
      c_lds[b * 17 + 2 * j]     = enc_c0[(size_t)b * U_ + u];
      c_lds[b * 17 + 2 * j + 1] = enc_c0[(size_t)b * U_ + u + 1];
    }
    __syncthreads();   // drains vmcnt(0): h0 stores complete at LLC
    if (tid == 0)
      __hip_atomic_fetch_add(&hcnt[0], 1u, __ATOMIC_RELAXED, __HIP_MEMORY_SCOPE_AGENT);

    for (int t = 0; t < T_; ++t) {
      // prefetch Zx (bf16, independent of the flag) — 4 u32, one per gate
      const unsigned short* zxbase = Zx + ((size_t)(t * B_ + b)) * FU_ + g * 16 + 2 * j;
      unsigned zxp0 = *(const unsigned*)(zxbase + 0 * U_);
      unsigned zxp1 = *(const unsigned*)(zxbase + 1 * U_);
      unsigned zxp2 = *(const unsigned*)(zxbase + 2 * U_);
      unsigned zxp3 = *(const unsigned*)(zxbase + 3 * U_);

      // wait for h[t] fully published
      if (tid == 0) {
        while (__hip_atomic_load(&hcnt[t * 16], __ATOMIC_RELAXED,
                                 __HIP_MEMORY_SCOPE_AGENT) < 32u)
          __builtin_amdgcn_s_sleep(1);
      }
      __syncthreads();

      // stage h[t] (32KB) LLC -> LDS. Two-phase: issue ALL 16 u64 loads first
      // (independent, pipelined in one vmcnt window), THEN the 16 ds_writes.
      // The old fused loop serialized load->wait->ds_write 16x (~5-6us/step).
      const unsigned long long* hp = hseq64 + (size_t)t * (B_ * U_ / 4);
      unsigned long long hv[16];
#pragma unroll
      for (int i = 0; i < 16; ++i) {
        hv[i] = __hip_atomic_load(&hp[i * 256 + tid], __ATOMIC_RELAXED,
                                  __HIP_MEMORY_SCOPE_AGENT);
      }
#pragma unroll
      for (int i = 0; i < 16; ++i) {
        int idx = i * 256 + tid;            // 0..4095
        int hb = idx >> 7, u0 = (idx & 127) * 4;
        *(unsigned long long*)&h_lds[hb * 520 + u0] = hv[i];
      }
      __syncthreads();

      // z-slice = h @ W_h  (wave w -> gate w, cols w*512 + g*16 + [0,16))
      f32x4 acc0 = {0.f, 0.f, 0.f, 0.f}, acc1 = {0.f, 0.f, 0.f, 0.f};
#pragma unroll
      for (int kc = 0; kc < 16; ++kc) {
        bf16x8 a0 = *(const bf16x8*)&h_lds[l15 * 520 + kc * 32 + quad * 8];
        bf16x8 a1 = *(const bf16x8*)&h_lds[(16 + l15) * 520 + kc * 32 + quad * 8];
        acc0 = __builtin_amdgcn_mfma_f32_16x16x32_bf16(a0, bfr[kc], acc0, 0, 0, 0);
        acc1 = __builtin_amdgcn_mfma_f32_16x16x32_bf16(a1, bfr[kc], acc1, 0, 0, 0);
      }
#pragma unroll
      for (int r = 0; r < 4; ++r) {
        z_lds[(quad * 4 + r) * 68 + w * 16 + l15] = acc0[r];
        z_lds[(16 + quad * 4 + r) * 68 + w * 16 + l15] = acc1[r];
      }
      __syncthreads();

      // gates + state update for (b, 2j) and (b, 2j+1)
      {
        int up0 = 2 * j, up1 = 2 * j + 1;
        float zi0 = z_lds[b * 68 + 0 + up0] + bf2f((unsigned short)(zxp0 & 0xFFFFu));
        float zi1 = z_lds[b * 68 + 0 + up1] + bf2f((unsigned short)(zxp0 >> 16));
        float zf0 = z_lds[b * 68 + 16 + up0] + bf2f((unsigned short)(zxp1 & 0xFFFFu));
        float zf1 = z_lds[b * 68 + 16 + up1] + bf2f((unsigned short)(zxp1 >> 16));
        float zg0 = z_lds[b * 68 + 32 + up0] + bf2f((unsigned short)(zxp2 & 0xFFFFu));
        float zg1 = z_lds[b * 68 + 32 + up1] + bf2f((unsigned short)(zxp2 >> 16));
        float zo0 = z_lds[b * 68 + 48 + up0] + bf2f((unsigned short)(zxp3 & 0xFFFFu));
        float zo1 = z_lds[b * 68 + 48 + up1] + bf2f((unsigned short)(zxp3 >> 16));
        float i0 = fast_sigmoid(zi0), i1 = fast_sigmoid(zi1);
        float f0 = fast_sigmoid(zf0), f1 = fast_sigmoid(zf1);
        float g0 = fast_tanh(zg0),    g1 = fast_tanh(zg1);
        float o0 = fast_sigmoid(zo0), o1 = fast_sigmoid(zo1);
        float c0 = f0 * c_lds[b * 17 + up0] + i0 * g0;
        float c1 = f1 * c_lds[b * 17 + up1] + i1 * g1;
        c_lds[b * 17 + up0] = c0;
        c_lds[b * 17 + up1] = c1;
        float h0 = o0 * fast_tanh(c0);
        float h1 = o1 * fast_tanh(c1);
        unsigned pack = (unsigned)f2bf(h0) | ((unsigned)f2bf(h1) << 16);
        __hip_atomic_store(&hseq32[(size_t)(t + 1) * (B_ * U_ / 2) + b * 256 + g * 8 + j],
                           pack, __ATOMIC_RELAXED, __HIP_MEMORY_SCOPE_AGENT);
        // h-half of Afc: agent-scope so folded-FC blocks see it at LLC
        __hip_atomic_store(
            (unsigned*)&Afc[(size_t)(t * B_ + b) * KFC_ + U_ + g * 16 + 2 * j],
            pack, __ATOMIC_RELAXED, __HIP_MEMORY_SCOPE_AGENT);
      }
      __syncthreads();   // drains vmcnt(0): publish stores complete at LLC
      if (tid == 0)
        __hip_atomic_fetch_add(&hcnt[(t + 1) * 16], 1u,
                               __ATOMIC_RELAXED, __HIP_MEMORY_SCOPE_AGENT);
    }
  } else if (blockIdx.x < 64) {
    // ---------------- consumer: attention for batch b ----------------
    float* h_sh    = (float*)smem;            // 512 f32 = 2048 B
    float* sc_part = (float*)(smem + 2048);   // 256 f32 = 1024 B
    float* probs   = (float*)(smem + 3072);   // 64 f32  = 256 B

    __builtin_amdgcn_s_setprio(1);
    const int b = blockIdx.x - 32;
    for (int t = 0; t < T_; ++t) {
      if (tid == 0) {
        while (__hip_atomic_load(&hcnt[(t + 1) * 16], __ATOMIC_RELAXED,
                                 __HIP_MEMORY_SCOPE_AGENT) < 32u)
          __builtin_amdgcn_s_sleep(2);
      }
      __syncthreads();
      // read h[t+1][b] (512 bf16 = 128 u64)
      if (tid < 128) {
        unsigned long long v = __hip_atomic_load(
            &hseq64[(size_t)(t + 1) * (B_ * U_ / 4) + b * 128 + tid],
            __ATOMIC_RELAXED, __HIP_MEMORY_SCOPE_AGENT);
        int u0 = tid * 4;
        h_sh[u0 + 0] = bf2f((unsigned short)(v & 0xFFFFu));
        h_sh[u0 + 1] = bf2f((unsigned short)((v >> 16) & 0xFFFFu));
        h_sh[u0 + 2] = bf2f((unsigned short)((v >> 32) & 0xFFFFu));
        h_sh[u0 + 3] = bf2f((unsigned short)((v >> 48) & 0xFFFFu));
      }
      __syncthreads();
      // score[l] = h . enc_proj[b,l,:]
      {
        int l = tid & 63, part = tid >> 6;
        const float* ep = enc_proj + ((size_t)(b * L_ + l)) * U_ + part * 128;
        const float* hs = h_sh + part * 128;
        float s = 0.f;
#pragma unroll 8
        for (int u = 0; u < 128; u += 4) {
          f32x4 e = *(const f32x4*)(ep + u);
          s += hs[u] * e[0] + hs[u + 1] * e[1] + hs[u + 2] * e[2] + hs[u + 3] * e[3];
        }
        sc_part[part * L_ + l] = s;
      }
      __syncthreads();
      if (tid < 64) {
        float s = sc_part[tid] + sc_part[64 + tid] + sc_part[128 + tid] + sc_part[192 + tid];
        float m = s;
#pragma unroll
        for (int off = 32; off >= 1; off >>= 1) m = fmaxf(m, __shfl_xor(m, off));
        float e = __expf(s - m);
        float sum = e;
#pragma unroll
        for (int off = 32; off >= 1; off >>= 1) sum += __shfl_xor(sum, off);
        probs[tid] = e / sum;
      }
      __syncthreads();
      // ctx = attn^T enc_out[b] via encT; u0 = 2*tid, 2*tid+1; packed atomic store
      {
        int u0 = 2 * tid;
        const unsigned short* ep0 = encT + ((size_t)b * U_ + u0) * L_;
        float c0 = 0.f, c1 = 0.f;
#pragma unroll
        for (int l8 = 0; l8 < 8; ++l8) {
          bf16x8 e0 = *(const bf16x8*)(ep0 + l8 * 8);
          bf16x8 e1 = *(const bf16x8*)(ep0 + L_ + l8 * 8);
#pragma unroll
          for (int q = 0; q < 8; ++q) {
            float p = probs[l8 * 8 + q];
            c0 += p * (float)e0[q];
            c1 += p * (float)e1[q];
          }
        }
        unsigned pack = (unsigned)f2bf(c0) | ((unsigned)f2bf(c1) << 16);
        __hip_atomic_store((unsigned*)&Afc[(size_t)(t * B_ + b) * KFC_ + u0], pack,
                           __ATOMIC_RELAXED, __HIP_MEMORY_SCOPE_AGENT);
      }
      __syncthreads();   // drains vmcnt(0): ctx stores complete at LLC
      if (tid == 0)
        __hip_atomic_fetch_add(&hcnt[CCNT_BASE + t * 16], 1u,
                               __ATOMIC_RELAXED, __HIP_MEMORY_SCOPE_AGENT);
    }
  } else {
    // ---------------- folded FC: (2016x1024) @ (1024x32000) bf16 MFMA ----------
    unsigned short* At = (unsigned short*)smem;           // 8192 B
    unsigned short* Bt = (unsigned short*)(smem + 8192);  // 8192 B
    float* rs = (float*)(smem + 16384);                   // 512 B
    float* lsb = (float*)(smem + 16896);                  // 4 B (broadcast)

    const int idx = blockIdx.x - 64;       // 0..3999, ry-major in dispatch order
    const int cx = idx % NFCX_, ry = idx / NFCX_;
    int t_hi = 4 * ry + 3; if (t_hi > T_ - 1) t_hi = T_ - 1;

    if (ry == 0) {
      // ---- transpose W_fc B-panel cx -> WfcT rows [cx*128, cx*128+128)
      // (hidden under early recurrence; publishes via agent atomics + flag)
      float* tile = (float*)smem;          // 32 x 132 f32 = 16896 B
      const int n0 = cx * 128;
      for (int kt2 = 0; kt2 < 32; ++kt2) {
        int k0 = kt2 * 32;
#pragma unroll
        for (int it = 0; it < 4; ++it) {
          int lin = it * 256 + tid;        // 0..1023
          int k = lin >> 5, nq = lin & 31;
          f32x4 v = *(const f32x4*)(W_fc + (size_t)(k0 + k) * V_ + n0 + nq * 4);
          *(f32x4*)&tile[k * 132 + nq * 4] = v;
        }
        __syncthreads();
#pragma unroll
        for (int it = 0; it < 4; ++it) {
          int lin = it * 256 + tid;
          int n = lin >> 3, kq = lin & 7;
          float a0 = tile[(kq * 4 + 0) * 132 + n];
          float a1 = tile[(kq * 4 + 1) * 132 + n];
          float a2 = tile[(kq * 4 + 2) * 132 + n];
          float a3 = tile[(kq * 4 + 3) * 132 + n];
          unsigned long long pk =
              (unsigned long long)((unsigned)f2bf(a0) | ((unsigned)f2bf(a1) << 16)) |
              ((unsigned long long)((unsigned)f2bf(a2) | ((unsigned)f2bf(a3) << 16)) << 32);
          __hip_atomic_store(
              (unsigned long long*)&WfcT[(size_t)(n0 + n) * KFC_ + k0 + kq * 4], pk,
              __ATOMIC_RELAXED, __HIP_MEMORY_SCOPE_AGENT);
        }
        __syncthreads();   // also drains vmcnt for this tile's stores
      }
      if (tid == 0)
        __hip_atomic_store(&AfcFlags[cx * 16], 1u,
                           __ATOMIC_RELAXED, __HIP_MEMORY_SCOPE_AGENT);
    }

    // wait: B-panel ready (ry>0) AND consumer step t_hi complete
    if (tid == 0) {
      if (ry != 0) {
        while (__hip_atomic_load(&AfcFlags[cx * 16], __ATOMIC_RELAXED,
                                 __HIP_MEMORY_SCOPE_AGENT) == 0u)
          __builtin_amdgcn_s_sleep(16);
      }
      while (__hip_atomic_load(&hcnt[CCNT_BASE + t_hi * 16], __ATOMIC_RELAXED,
                               __HIP_MEMORY_SCOPE_AGENT) < 32u)
        __builtin_amdgcn_s_sleep(32);
    }
    __syncthreads();

    const int w = tid >> 6, lane = tid & 63, quad = lane >> 4, l15 = lane & 15;
    const int row0 = ry * 128, col0 = cx * 128;
    const int mh = (w >> 1) * 64, nh = (w & 1) * 64;

    f32x4 acc[4][4];
#pragma unroll
    for (int i = 0; i < 4; ++i)
#pragma unroll
      for (int j = 0; j < 4; ++j) { f32x4 z = {0.f, 0.f, 0.f, 0.f}; acc[i][j] = z; }

    for (int kt = 0; kt < KFC_ / 32; ++kt) {
      int k0 = kt * 32;
#pragma unroll
      for (int i = 0; i < 2; ++i) {
        int lin = i * 256 + tid;
        int r = lin >> 2, s = lin & 3;
        int gseg = (s - (r >> 1)) & 3;     // XOR swizzle
        f32x4 va = *(const f32x4*)(Afc + ((size_t)(row0 + r)) * KFC_ + k0 + gseg * 8);
        *(f32x4*)&At[r * 32 + s * 8] = va;
        f32x4 vb = *(const f32x4*)(WfcT + ((size_t)(col0 + r)) * KFC_ + k0 + gseg * 8);
        *(f32x4*)&Bt[r * 32 + s * 8] = vb;
      }
      __syncthreads();
      bf16x8 a[4], b[4];
#pragma unroll
      for (int i = 0; i < 4; ++i) {
        int m = mh + i * 16 + l15;
        a[i] = *(const bf16x8*)&At[m * 32 + (((quad + (m >> 1)) & 3) * 8)];
        int n = nh + i * 16 + l15;
        b[i] = *(const bf16x8*)&Bt[n * 32 + (((quad + (n >> 1)) & 3) * 8)];
      }
#pragma unroll
      for (int i = 0; i < 4; ++i)
#pragma unroll
        for (int j = 0; j < 4; ++j)
          acc[i][j] = __builtin_amdgcn_mfma_f32_16x16x32_bf16(a[i], b[j], acc[i][j], 0, 0, 0);
      __syncthreads();
    }

    if (tid < 128) rs[tid] = 0.f;
    __syncthreads();
    float bv[4];
#pragma unroll
    for (int j = 0; j < 4; ++j) bv[j] = b_fc[col0 + nh + j * 16 + l15];
    float rp[4][4];
#pragma unroll
    for (int i = 0; i < 4; ++i)
#pragma unroll
      for (int r = 0; r < 4; ++r) rp[i][r] = 0.f;
#pragma unroll
    for (int i = 0; i < 4; ++i) {
#pragma unroll
      for (int j = 0; j < 4; ++j) {
        int cg = col0 + nh + j * 16 + l15;
#pragma unroll
        for (int r = 0; r < 4; ++r) {
          float val = fast_tanh(acc[i][j][r] + bv[j]);
          int rg = row0 + mh + i * 16 + quad * 4 + r;
          if (rg < MROW_) {
            int b = rg & 31, t = rg >> 5;
            union { float f; unsigned u; } cv; cv.f = val;
            // agent-scope: folded normalizer blocks must see these at LLC
            __hip_atomic_store(
                (unsigned*)&out[((size_t)(b * T_ + t)) * V_ + cg], cv.u,
                __ATOMIC_RELAXED, __HIP_MEMORY_SCOPE_AGENT);
          }
          rp[i][r] += __expf(val);
        }
      }
    }
#pragma unroll
    for (int i = 0; i < 4; ++i)
#pragma unroll
      for (int r = 0; r < 4; ++r) {
        float v = rp[i][r];
        v += __shfl_xor(v, 1); v += __shfl_xor(v, 2);
        v += __shfl_xor(v, 4); v += __shfl_xor(v, 8);
        if (l15 == 0) atomicAdd(&rs[mh + i * 16 + quad * 4 + r], v);
      }
    __syncthreads();
    if (tid < 128) {
      int rg = row0 + tid;
      if (rg < MROW_) atomicAdd(&row_sums[rg], rs[tid]);
    }
    __syncthreads();   // drains vmcnt(0): out stores + row_sums adds at LLC
    if (tid == 0)
      __hip_atomic_fetch_add(&AfcFlags[4096 + ry * 16], 1u,
                             __ATOMIC_RELAXED, __HIP_MEMORY_SCOPE_AGENT);

    // ---- folded log-softmax normalize (replaces k_lsm): cx<128 handles one row
    {
      int rg = ry * 128 + cx;
      if (cx < 128 && rg < MROW_) {
        if (tid == 0) {
          while (__hip_atomic_load(&AfcFlags[4096 + ry * 16], __ATOMIC_RELAXED,
                                   __HIP_MEMORY_SCOPE_AGENT) < (unsigned)NFCX_)
            __builtin_amdgcn_s_sleep(16);
          union { unsigned u; float f; } cv;
          cv.u = __hip_atomic_load((unsigned*)&row_sums[rg], __ATOMIC_RELAXED,
                                   __HIP_MEMORY_SCOPE_AGENT);
          lsb[0] = __logf(cv.f);
        }
        __syncthreads();
        float ls = lsb[0];
        int b = rg & 31, t = rg >> 5;
        float* orow = out + (size_t)(b * T_ + t) * V_;
        for (int c = tid * 4; c < V_; c += 1024) {
          f32x4 v = *(const f32x4*)(orow + c);
          v[0] -= ls; v[1] -= ls; v[2] -= ls; v[3] -= ls;
          *(f32x4*)(orow + c) = v;   // plain: kernel-end flush covers harness read
        }
      }
    }
  }
}

// ---------------------------------------------------------------- launch
extern "C" void kernel_launch(void* const* d_in, const int* in_sizes, int n_in,
                              void* d_out, int out_size, void* d_ws, size_t ws_size,
                              hipStream_t stream) {
  const int*   target  = (const int*)d_in[0];
  const float* enc_out = (const float*)d_in[1];
  const float* enc_h0  = (const float*)d_in[2];
  const float* enc_c0  = (const float*)d_in[3];
  const float* emb     = (const float*)d_in[4];
  const float* W_x     = (const float*)d_in[5];
  const float* W_h     = (const float*)d_in[6];
  const float* b_lstm  = (const float*)d_in[7];
  const float* Wa      = (const float*)d_in[8];
  const float* W_fc    = (const float*)d_in[9];
  const float* b_fc    = (const float*)d_in[10];
  float* out = (float*)d_out;
  char* ws = (char*)d_ws;

  // ws layout (bytes); total ~84.4 MiB (unchanged from prior round)
  unsigned int*   hcnt     = (unsigned int*)(ws + 0);             // 2048 u32
  float*          row_sums = (float*)(ws + 8192);                 // 2016 f32
  unsigned short* fragWh   = (unsigned short*)(ws + 16384);       // 2 MiB
  unsigned int*   hseq32   = (unsigned int*)(ws + 2113536);       // 2 MiB (64 steps)
  unsigned short* Zx       = (unsigned short*)(ws + 4210688);     // 8.25 MB (bf16)
  float*          enc_proj = (float*)(ws + 12468224);             // 4 MiB
  unsigned short* Afc      = (unsigned short*)(ws + 16662528);    // 4 MiB (2048x1024)
  unsigned short* encT     = (unsigned short*)(ws + 20856832);    // 2 MiB (bf16)
  unsigned short* WfcT     = (unsigned short*)(ws + 22953984);    // 62.5 MiB

  unsigned int* AfcFlags = (unsigned int*)(ws + 16662528 + (size_t)AFC_FLAG_U32 * 4);

  // 2 launches: prep (small precompute), rec (everything else, flag-gated).
  k_prep <<<dim3(1536),         dim3(256), 0, stream>>>(target, emb, W_x, b_lstm,
                                                        enc_out, Wa, W_h,
                                                        fragWh, Zx, enc_proj, encT,
                                                        hcnt, row_sums, AfcFlags);
  k_rec  <<<dim3(64 + NFCX_ * NFCY_), dim3(256), 0, stream>>>(enc_h0, enc_c0,
                                                        enc_proj, Zx, fragWh, encT,
                                                        hseq32, Afc, hcnt,
                                                        WfcT, b_fc, out, row_sums,
                                                        W_fc);
}

// Round 4
// 1063.665 us; speedup vs baseline: 1.2377x; 1.2377x over previous
//
#include <hip/hip_runtime.h>
#include <stdint.h>

// Problem constants (from reference)
#define B_   32
#define T_   63      // S-1
#define U_   512
#define E_   256
#define V_   32000
#define L_   64
#define FU_  2048    // 4U
#define KFC_ 1024    // 2U
#define MROW_ 2016   // B*T

// FC fold geometry
#define NFCX_ 250    // 32000/128 col panels
#define NFCY_ 16     // 2048/128 row panels
#define CCNT_BASE 1024   // ccnt[t] lives at hcnt[CCNT_BASE + t*16]
// flags in Afc's unused rows 2016..2047 (u32 view): wfcTrdy[cx] at [cx*16].
#define AFC_FLAG_U32 (2016 * 512)

typedef float f32x4 __attribute__((ext_vector_type(4)));
typedef float f32x2 __attribute__((ext_vector_type(2)));
typedef __bf16 bf16x8 __attribute__((ext_vector_type(8)));

__device__ __forceinline__ unsigned short f2bf(float f) {
  union { float f; unsigned u; } v; v.f = f;
  unsigned u = v.u;
  u += 0x7FFFu + ((u >> 16) & 1u);   // round-to-nearest-even
  return (unsigned short)(u >> 16);
}
__device__ __forceinline__ float bf2f(unsigned short h) {
  union { unsigned u; float f; } v; v.u = ((unsigned)h) << 16;
  return v.f;
}
__device__ __forceinline__ float fast_sigmoid(float x) {
  return 1.f / (1.f + __expf(-x));
}
__device__ __forceinline__ float fast_tanh(float x) {
  float e = __expf(2.f * x);          // x>>0: e=inf -> 1; x<<0: e=0 -> -1
  return 1.f - 2.f / (e + 1.f);
}

// ---------------------------------------------------------------- k_prep
// Precompute (W_fc transpose folded into k_rec):
//   [0,512)      fragWh : W_h -> MFMA B-fragment layout (bf16)
//   [512,1016)   zx     : Zx[t][b] = bf16(emb[target] @ W_x + b_lstm)
//   [1016,1272)  encproj: enc_out @ Wa (f32)
//   [1272,1528)  encT   : enc_out transposed to [b][u][l] bf16
//   [1528,1536)  zero   : hcnt + ccnt + Afc-flag region + row_sums
__global__ __launch_bounds__(256) void k_prep(const int* __restrict__ target,
    const float* __restrict__ emb, const float* __restrict__ W_x,
    const float* __restrict__ b_lstm, const float* __restrict__ enc_out,
    const float* __restrict__ Wa, const float* __restrict__ W_h,
    unsigned short* __restrict__ fragWh, unsigned short* __restrict__ Zx,
    float* __restrict__ enc_proj, unsigned short* __restrict__ encT,
    unsigned int* __restrict__ hcnt, float* __restrict__ row_sums,
    unsigned int* __restrict__ AfcFlags) {
  __shared__ __align__(16) char smem[32768];
  const int bx = blockIdx.x;
  const int tid = threadIdx.x;

  if (bx < 512) {
    // ---- fragWh[ct][kc][lane][j] = bf16(W_h[kc*32+(lane>>4)*8+j][ct*16+(lane&15)])
    int idx = bx * 256 + tid;   // 0..131071
    int lane = idx & 63;
    int kc   = (idx >> 6) & 15;
    int ct   = idx >> 10;
    int quad = lane >> 4, l15 = lane & 15;
    int col = ct * 16 + l15;
    unsigned short* dst = fragWh + (size_t)idx * 8;
#pragma unroll
    for (int j = 0; j < 8; ++j) {
      int k = kc * 32 + quad * 8 + j;
      dst[j] = f2bf(W_h[(size_t)k * FU_ + col]);
    }
  } else if (bx < 1016) {
    // ---- Zx
    float* x_lds = (float*)smem;          // 32 KB
    int r = bx - 512;                     // 0..503
    int t = r % 63, cc = r / 63;
    for (int i = tid; i < B_ * E_; i += 256) {
      int b = i >> 8, e = i & 255;
      x_lds[i] = emb[(size_t)target[b * 64 + t] * E_ + e];
    }
    __syncthreads();
    int col = cc * 256 + tid;
    float acc[B_];
#pragma unroll
    for (int b = 0; b < B_; ++b) acc[b] = 0.f;
    for (int e4 = 0; e4 < E_ / 4; ++e4) {
      float w0 = W_x[(size_t)(4 * e4 + 0) * FU_ + col];
      float w1 = W_x[(size_t)(4 * e4 + 1) * FU_ + col];
      float w2 = W_x[(size_t)(4 * e4 + 2) * FU_ + col];
      float w3 = W_x[(size_t)(4 * e4 + 3) * FU_ + col];
#pragma unroll
      for (int b = 0; b < B_; ++b) {
        f32x4 xv = *(const f32x4*)&x_lds[b * E_ + 4 * e4];
        acc[b] += xv[0] * w0 + xv[1] * w1 + xv[2] * w2 + xv[3] * w3;
      }
    }
    float bias = b_lstm[col];
#pragma unroll
    for (int b = 0; b < B_; ++b)
      Zx[((size_t)(t * B_ + b)) * FU_ + col] = f2bf(acc[b] + bias);
  } else if (bx < 1272) {
    // ---- enc_proj
    float* e_lds = (float*)smem;          // 32 KB
    int r = bx - 1016;                    // 0..255
    int rc = r & 127, cc = r >> 7;
    int row0 = rc * 16;
    for (int i = tid; i < 16 * U_; i += 256)
      e_lds[i] = enc_out[(size_t)(row0 + (i >> 9)) * U_ + (i & 511)];
    __syncthreads();
    int col = cc * 256 + tid;
    float acc[16];
#pragma unroll
    for (int q = 0; q < 16; ++q) acc[q] = 0.f;
    for (int k4 = 0; k4 < U_ / 4; ++k4) {
      float w0 = Wa[(size_t)(4 * k4 + 0) * U_ + col];
      float w1 = Wa[(size_t)(4 * k4 + 1) * U_ + col];
      float w2 = Wa[(size_t)(4 * k4 + 2) * U_ + col];
      float w3 = Wa[(size_t)(4 * k4 + 3) * U_ + col];
#pragma unroll
      for (int q = 0; q < 16; ++q) {
        f32x4 xv = *(const f32x4*)&e_lds[q * U_ + 4 * k4];
        acc[q] += xv[0] * w0 + xv[1] * w1 + xv[2] * w2 + xv[3] * w3;
      }
    }
#pragma unroll
    for (int q = 0; q < 16; ++q)
      enc_proj[(size_t)(row0 + q) * U_ + col] = acc[q];
  } else if (bx < 1528) {
    // ---- encT[b][u][l] = bf16(enc_out[b][l][u])
    float (*tile)[65] = (float(*)[65])smem;   // 64x65 f32 = 16.6 KB
    int r = bx - 1272;                        // 0..255
    int b = r & 31, uc = r >> 5;
#pragma unroll
    for (int i = 0; i < 16; ++i) {
      int idx = i * 256 + tid;            // 0..4095
      int l = idx >> 6, u = idx & 63;
      tile[l][u] = enc_out[((size_t)b * L_ + l) * U_ + uc * 64 + u];
    }
    __syncthreads();
#pragma unroll
    for (int i = 0; i < 16; ++i) {
      int idx = i * 256 + tid;
      int u = idx >> 6, l = idx & 63;
      encT[((size_t)b * U_ + uc * 64 + u) * L_ + l] = f2bf(tile[l][u]);
    }
  } else {
    // ---- zero flags (hcnt + ccnt) + Afc flag region + row_sums
    int i = (bx - 1528) * 256 + tid;      // 0..2047
    hcnt[i] = 0u;
    if (i < MROW_) row_sums[i] = 0.f;
    AfcFlags[i * 4 + 0] = 0u;
    AfcFlags[i * 4 + 1] = 0u;
    AfcFlags[i * 4 + 2] = 0u;
    AfcFlags[i * 4 + 3] = 0u;
  }
}

// ---------------------------------------------------------------- k_rec
// 4064 blocks x 256 threads, single launch.
//   blocks 0..31    (g): LSTM producers — u-slice [g*16, g*16+16) of all 4 gates.
//   blocks 32..63   (b): attention consumers — batch element b, all 63 steps.
//   blocks 64..4063   : folded FC GEMM tiles, flag-gated on consumer progress.
//     ry==0 blocks additionally transpose their W_fc B-panel first (hidden
//     under early recurrence steps).
// Log-softmax normalization is a SEPARATE kernel (k_lsm): folding it here
// (R3) made cx<128 blocks spin-block residency slots waiting on fcdone and
// forced write-through scalar out stores — k_rec 650->950us regression.
// All cross-block data goes through LLC with relaxed agent-scope atomics;
// __syncthreads() drains vmcnt(0) before each flag publish (proven pattern).
__global__ __launch_bounds__(256, 1) void k_rec(const float* __restrict__ enc_h0,
    const float* __restrict__ enc_c0,
    const float* __restrict__ enc_proj, const unsigned short* __restrict__ Zx,
    const unsigned short* __restrict__ fragWh, const unsigned short* __restrict__ encT,
    unsigned int* hseq32,                  // 64 steps x (B_*U_/2) u32 (bf16 pairs)
    unsigned short* __restrict__ Afc,      // 2048 x 1024 bf16 [ctx | h] + flag rows
    unsigned int* hcnt,                    // flags: hcnt[t*16]; ccnt at [1024+t*16]
    unsigned short* __restrict__ WfcT, const float* __restrict__ b_fc,
    float* __restrict__ out, float* __restrict__ row_sums,
    const float* __restrict__ W_fc) {
  // LDS union: producer 44160 B | consumer 3328 B | fc 16896 B
  __shared__ __align__(16) char smem[44160];

  const int tid = threadIdx.x;
  unsigned long long* hseq64 = (unsigned long long*)hseq32;
  unsigned int* AfcFlags = (unsigned int*)Afc + AFC_FLAG_U32;

  if (blockIdx.x < 32) {
    // ---------------- producer ----------------
    unsigned short* h_lds = (unsigned short*)smem;        // 32 x 520 u16 = 33280 B
    float* z_lds = (float*)(smem + 33280);                // 32 x 68 f32 = 8704 B
    float* c_lds = (float*)(smem + 41984);                // 32 x 17 f32 = 2176 B

    const int g = blockIdx.x;
    const int w = tid >> 6;
    const int lane = tid & 63;
    const int quad = lane >> 4;
    const int l15 = lane & 15;
    const int b = tid >> 3;      // gate-phase mapping: 32 b x 8 j
    const int j = tid & 7;       // u = g*16 + 2j, 2j+1

    // hoist step-invariant W_h B-fragments into registers (64 VGPRs)
    const unsigned short* bbase = fragWh + ((size_t)(w * 32 + g) * 16) * 64 * 8;
    bf16x8 bfr[16];
#pragma unroll
    for (int kc = 0; kc < 16; ++kc)
      bfr[kc] = *(const bf16x8*)(bbase + (size_t)(kc * 64 + lane) * 8);

    // latency-critical waves: preferential issue vs co-resident FC waves
    __builtin_amdgcn_s_setprio(1);

    // init: c slice -> LDS (fp32, persistent); h0 slice -> hseq[0]
    {
      int u = g * 16 + 2 * j;
      float h0a = enc_h0[(size_t)b * U_ + u];
      float h0b = enc_h0[(size_t)b * U_ + u + 1];
      unsigned pack = (unsigned)f2bf(h0a) | ((unsigned)f2bf(h0b) << 16);
      __hip_atomic_store(&hseq32[b * 256 + g * 8 + j], pack,
                         __ATOMIC_RELAXED, __HIP_MEMORY_SCOPE_AGENT);
      c_lds[b * 17 + 2 * j]     = enc_c0[(size_t)b * U_ + u];
      c_lds[b * 17 + 2 * j + 1] = enc_c0[(size_t)b * U_ + u + 1];
    }
    __syncthreads();   // drains vmcnt(0): h0 stores complete at LLC
    if (tid == 0)
      __hip_atomic_fetch_add(&hcnt[0], 1u, __ATOMIC_RELAXED, __HIP_MEMORY_SCOPE_AGENT);

    for (int t = 0; t < T_; ++t) {
      // prefetch Zx (bf16, independent of the flag) — 4 u32, one per gate
      const unsigned short* zxbase = Zx + ((size_t)(t * B_ + b)) * FU_ + g * 16 + 2 * j;
      unsigned zxp0 = *(const unsigned*)(zxbase + 0 * U_);
      unsigned zxp1 = *(const unsigned*)(zxbase + 1 * U_);
      unsigned zxp2 = *(const unsigned*)(zxbase + 2 * U_);
      unsigned zxp3 = *(const unsigned*)(zxbase + 3 * U_);

      // wait for h[t] fully published
      if (tid == 0) {
        while (__hip_atomic_load(&hcnt[t * 16], __ATOMIC_RELAXED,
                                 __HIP_MEMORY_SCOPE_AGENT) < 32u)
          __builtin_amdgcn_s_sleep(1);
      }
      __syncthreads();

      // stage h[t] (32KB) LLC -> LDS. Two-phase: issue ALL 16 u64 loads first
      // (independent, pipelined in one vmcnt window), THEN the 16 ds_writes.
      const unsigned long long* hp = hseq64 + (size_t)t * (B_ * U_ / 4);
      unsigned long long hv[16];
#pragma unroll
      for (int i = 0; i < 16; ++i) {
        hv[i] = __hip_atomic_load(&hp[i * 256 + tid], __ATOMIC_RELAXED,
                                  __HIP_MEMORY_SCOPE_AGENT);
      }
#pragma unroll
      for (int i = 0; i < 16; ++i) {
        int idx = i * 256 + tid;            // 0..4095
        int hb = idx >> 7, u0 = (idx & 127) * 4;
        *(unsigned long long*)&h_lds[hb * 520 + u0] = hv[i];
      }
      __syncthreads();

      // z-slice = h @ W_h  (wave w -> gate w, cols w*512 + g*16 + [0,16))
      f32x4 acc0 = {0.f, 0.f, 0.f, 0.f}, acc1 = {0.f, 0.f, 0.f, 0.f};
#pragma unroll
      for (int kc = 0; kc < 16; ++kc) {
        bf16x8 a0 = *(const bf16x8*)&h_lds[l15 * 520 + kc * 32 + quad * 8];
        bf16x8 a1 = *(const bf16x8*)&h_lds[(16 + l15) * 520 + kc * 32 + quad * 8];
        acc0 = __builtin_amdgcn_mfma_f32_16x16x32_bf16(a0, bfr[kc], acc0, 0, 0, 0);
        acc1 = __builtin_amdgcn_mfma_f32_16x16x32_bf16(a1, bfr[kc], acc1, 0, 0, 0);
      }
#pragma unroll
      for (int r = 0; r < 4; ++r) {
        z_lds[(quad * 4 + r) * 68 + w * 16 + l15] = acc0[r];
        z_lds[(16 + quad * 4 + r) * 68 + w * 16 + l15] = acc1[r];
      }
      __syncthreads();

      // gates + state update for (b, 2j) and (b, 2j+1)
      {
        int up0 = 2 * j, up1 = 2 * j + 1;
        float zi0 = z_lds[b * 68 + 0 + up0] + bf2f((unsigned short)(zxp0 & 0xFFFFu));
        float zi1 = z_lds[b * 68 + 0 + up1] + bf2f((unsigned short)(zxp0 >> 16));
        float zf0 = z_lds[b * 68 + 16 + up0] + bf2f((unsigned short)(zxp1 & 0xFFFFu));
        float zf1 = z_lds[b * 68 + 16 + up1] + bf2f((unsigned short)(zxp1 >> 16));
        float zg0 = z_lds[b * 68 + 32 + up0] + bf2f((unsigned short)(zxp2 & 0xFFFFu));
        float zg1 = z_lds[b * 68 + 32 + up1] + bf2f((unsigned short)(zxp2 >> 16));
        float zo0 = z_lds[b * 68 + 48 + up0] + bf2f((unsigned short)(zxp3 & 0xFFFFu));
        float zo1 = z_lds[b * 68 + 48 + up1] + bf2f((unsigned short)(zxp3 >> 16));
        float i0 = fast_sigmoid(zi0), i1 = fast_sigmoid(zi1);
        float f0 = fast_sigmoid(zf0), f1 = fast_sigmoid(zf1);
        float g0 = fast_tanh(zg0),    g1 = fast_tanh(zg1);
        float o0 = fast_sigmoid(zo0), o1 = fast_sigmoid(zo1);
        float c0 = f0 * c_lds[b * 17 + up0] + i0 * g0;
        float c1 = f1 * c_lds[b * 17 + up1] + i1 * g1;
        c_lds[b * 17 + up0] = c0;
        c_lds[b * 17 + up1] = c1;
        float h0 = o0 * fast_tanh(c0);
        float h1 = o1 * fast_tanh(c1);
        unsigned pack = (unsigned)f2bf(h0) | ((unsigned)f2bf(h1) << 16);
        __hip_atomic_store(&hseq32[(size_t)(t + 1) * (B_ * U_ / 2) + b * 256 + g * 8 + j],
                           pack, __ATOMIC_RELAXED, __HIP_MEMORY_SCOPE_AGENT);
        // h-half of Afc: agent-scope so folded-FC blocks see it at LLC
        __hip_atomic_store(
            (unsigned*)&Afc[(size_t)(t * B_ + b) * KFC_ + U_ + g * 16 + 2 * j],
            pack, __ATOMIC_RELAXED, __HIP_MEMORY_SCOPE_AGENT);
      }
      __syncthreads();   // drains vmcnt(0): publish stores complete at LLC
      if (tid == 0)
        __hip_atomic_fetch_add(&hcnt[(t + 1) * 16], 1u,
                               __ATOMIC_RELAXED, __HIP_MEMORY_SCOPE_AGENT);
    }
  } else if (blockIdx.x < 64) {
    // ---------------- consumer: attention for batch b ----------------
    float* h_sh    = (float*)smem;            // 512 f32 = 2048 B
    float* sc_part = (float*)(smem + 2048);   // 256 f32 = 1024 B
    float* probs   = (float*)(smem + 3072);   // 64 f32  = 256 B

    __builtin_amdgcn_s_setprio(1);
    const int b = blockIdx.x - 32;
    for (int t = 0; t < T_; ++t) {
      if (tid == 0) {
        while (__hip_atomic_load(&hcnt[(t + 1) * 16], __ATOMIC_RELAXED,
                                 __HIP_MEMORY_SCOPE_AGENT) < 32u)
          __builtin_amdgcn_s_sleep(2);
      }
      __syncthreads();
      // read h[t+1][b] (512 bf16 = 128 u64)
      if (tid < 128) {
        unsigned long long v = __hip_atomic_load(
            &hseq64[(size_t)(t + 1) * (B_ * U_ / 4) + b * 128 + tid],
            __ATOMIC_RELAXED, __HIP_MEMORY_SCOPE_AGENT);
        int u0 = tid * 4;
        h_sh[u0 + 0] = bf2f((unsigned short)(v & 0xFFFFu));
        h_sh[u0 + 1] = bf2f((unsigned short)((v >> 16) & 0xFFFFu));
        h_sh[u0 + 2] = bf2f((unsigned short)((v >> 32) & 0xFFFFu));
        h_sh[u0 + 3] = bf2f((unsigned short)((v >> 48) & 0xFFFFu));
      }
      __syncthreads();
      // score[l] = h . enc_proj[b,l,:]
      {
        int l = tid & 63, part = tid >> 6;
        const float* ep = enc_proj + ((size_t)(b * L_ + l)) * U_ + part * 128;
        const float* hs = h_sh + part * 128;
        float s = 0.f;
#pragma unroll 8
        for (int u = 0; u < 128; u += 4) {
          f32x4 e = *(const f32x4*)(ep + u);
          s += hs[u] * e[0] + hs[u + 1] * e[1] + hs[u + 2] * e[2] + hs[u + 3] * e[3];
        }
        sc_part[part * L_ + l] = s;
      }
      __syncthreads();
      if (tid < 64) {
        float s = sc_part[tid] + sc_part[64 + tid] + sc_part[128 + tid] + sc_part[192 + tid];
        float m = s;
#pragma unroll
        for (int off = 32; off >= 1; off >>= 1) m = fmaxf(m, __shfl_xor(m, off));
        float e = __expf(s - m);
        float sum = e;
#pragma unroll
        for (int off = 32; off >= 1; off >>= 1) sum += __shfl_xor(sum, off);
        probs[tid] = e / sum;
      }
      __syncthreads();
      // ctx = attn^T enc_out[b] via encT; u0 = 2*tid, 2*tid+1; packed atomic store
      {
        int u0 = 2 * tid;
        const unsigned short* ep0 = encT + ((size_t)b * U_ + u0) * L_;
        float c0 = 0.f, c1 = 0.f;
#pragma unroll
        for (int l8 = 0; l8 < 8; ++l8) {
          bf16x8 e0 = *(const bf16x8*)(ep0 + l8 * 8);
          bf16x8 e1 = *(const bf16x8*)(ep0 + L_ + l8 * 8);
#pragma unroll
          for (int q = 0; q < 8; ++q) {
            float p = probs[l8 * 8 + q];
            c0 += p * (float)e0[q];
            c1 += p * (float)e1[q];
          }
        }
        unsigned pack = (unsigned)f2bf(c0) | ((unsigned)f2bf(c1) << 16);
        __hip_atomic_store((unsigned*)&Afc[(size_t)(t * B_ + b) * KFC_ + u0], pack,
                           __ATOMIC_RELAXED, __HIP_MEMORY_SCOPE_AGENT);
      }
      __syncthreads();   // drains vmcnt(0): ctx stores complete at LLC
      if (tid == 0)
        __hip_atomic_fetch_add(&hcnt[CCNT_BASE + t * 16], 1u,
                               __ATOMIC_RELAXED, __HIP_MEMORY_SCOPE_AGENT);
    }
  } else {
    // ---------------- folded FC: (2016x1024) @ (1024x32000) bf16 MFMA ----------
    unsigned short* At = (unsigned short*)smem;           // 8192 B
    unsigned short* Bt = (unsigned short*)(smem + 8192);  // 8192 B
    float* rs = (float*)(smem + 16384);                   // 512 B

    const int idx = blockIdx.x - 64;       // 0..3999, ry-major in dispatch order
    const int cx = idx % NFCX_, ry = idx / NFCX_;
    int t_hi = 4 * ry + 3; if (t_hi > T_ - 1) t_hi = T_ - 1;

    if (ry == 0) {
      // ---- transpose W_fc B-panel cx -> WfcT rows [cx*128, cx*128+128)
      // (hidden under early recurrence; publishes via agent atomics + flag)
      float* tile = (float*)smem;          // 32 x 132 f32 = 16896 B
      const int n0 = cx * 128;
      for (int kt2 = 0; kt2 < 32; ++kt2) {
        int k0 = kt2 * 32;
#pragma unroll
        for (int it = 0; it < 4; ++it) {
          int lin = it * 256 + tid;        // 0..1023
          int k = lin >> 5, nq = lin & 31;
          f32x4 v = *(const f32x4*)(W_fc + (size_t)(k0 + k) * V_ + n0 + nq * 4);
          *(f32x4*)&tile[k * 132 + nq * 4] = v;
        }
        __syncthreads();
#pragma unroll
        for (int it = 0; it < 4; ++it) {
          int lin = it * 256 + tid;
          int n = lin >> 3, kq = lin & 7;
          float a0 = tile[(kq * 4 + 0) * 132 + n];
          float a1 = tile[(kq * 4 + 1) * 132 + n];
          float a2 = tile[(kq * 4 + 2) * 132 + n];
          float a3 = tile[(kq * 4 + 3) * 132 + n];
          unsigned long long pk =
              (unsigned long long)((unsigned)f2bf(a0) | ((unsigned)f2bf(a1) << 16)) |
              ((unsigned long long)((unsigned)f2bf(a2) | ((unsigned)f2bf(a3) << 16)) << 32);
          __hip_atomic_store(
              (unsigned long long*)&WfcT[(size_t)(n0 + n) * KFC_ + k0 + kq * 4], pk,
              __ATOMIC_RELAXED, __HIP_MEMORY_SCOPE_AGENT);
        }
        __syncthreads();   // also drains vmcnt for this tile's stores
      }
      if (tid == 0)
        __hip_atomic_store(&AfcFlags[cx * 16], 1u,
                           __ATOMIC_RELAXED, __HIP_MEMORY_SCOPE_AGENT);
    }

    // wait: B-panel ready (ry>0) AND consumer step t_hi complete
    if (tid == 0) {
      if (ry != 0) {
        while (__hip_atomic_load(&AfcFlags[cx * 16], __ATOMIC_RELAXED,
                                 __HIP_MEMORY_SCOPE_AGENT) == 0u)
          __builtin_amdgcn_s_sleep(16);
      }
      while (__hip_atomic_load(&hcnt[CCNT_BASE + t_hi * 16], __ATOMIC_RELAXED,
                               __HIP_MEMORY_SCOPE_AGENT) < 32u)
        __builtin_amdgcn_s_sleep(32);
    }
    __syncthreads();

    const int w = tid >> 6, lane = tid & 63, quad = lane >> 4, l15 = lane & 15;
    const int row0 = ry * 128, col0 = cx * 128;
    const int mh = (w >> 1) * 64, nh = (w & 1) * 64;

    f32x4 acc[4][4];
#pragma unroll
    for (int i = 0; i < 4; ++i)
#pragma unroll
      for (int j = 0; j < 4; ++j) { f32x4 z = {0.f, 0.f, 0.f, 0.f}; acc[i][j] = z; }

    for (int kt = 0; kt < KFC_ / 32; ++kt) {
      int k0 = kt * 32;
#pragma unroll
      for (int i = 0; i < 2; ++i) {
        int lin = i * 256 + tid;
        int r = lin >> 2, s = lin & 3;
        int gseg = (s - (r >> 1)) & 3;     // XOR swizzle
        f32x4 va = *(const f32x4*)(Afc + ((size_t)(row0 + r)) * KFC_ + k0 + gseg * 8);
        *(f32x4*)&At[r * 32 + s * 8] = va;
        f32x4 vb = *(const f32x4*)(WfcT + ((size_t)(col0 + r)) * KFC_ + k0 + gseg * 8);
        *(f32x4*)&Bt[r * 32 + s * 8] = vb;
      }
      __syncthreads();
      bf16x8 a[4], b[4];
#pragma unroll
      for (int i = 0; i < 4; ++i) {
        int m = mh + i * 16 + l15;
        a[i] = *(const bf16x8*)&At[m * 32 + (((quad + (m >> 1)) & 3) * 8)];
        int n = nh + i * 16 + l15;
        b[i] = *(const bf16x8*)&Bt[n * 32 + (((quad + (n >> 1)) & 3) * 8)];
      }
#pragma unroll
      for (int i = 0; i < 4; ++i)
#pragma unroll
        for (int j = 0; j < 4; ++j)
          acc[i][j] = __builtin_amdgcn_mfma_f32_16x16x32_bf16(a[i], b[j], acc[i][j], 0, 0, 0);
      __syncthreads();
    }

    if (tid < 128) rs[tid] = 0.f;
    __syncthreads();
    float bv[4];
#pragma unroll
    for (int j = 0; j < 4; ++j) bv[j] = b_fc[col0 + nh + j * 16 + l15];
    float rp[4][4];
#pragma unroll
    for (int i = 0; i < 4; ++i)
#pragma unroll
      for (int r = 0; r < 4; ++r) rp[i][r] = 0.f;
#pragma unroll
    for (int i = 0; i < 4; ++i) {
#pragma unroll
      for (int j = 0; j < 4; ++j) {
        int cg = col0 + nh + j * 16 + l15;
#pragma unroll
        for (int r = 0; r < 4; ++r) {
          float val = fast_tanh(acc[i][j][r] + bv[j]);
          int rg = row0 + mh + i * 16 + quad * 4 + r;
          if (rg < MROW_) {
            int b = rg & 31, t = rg >> 5;
            out[((size_t)(b * T_ + t)) * V_ + cg] = val;   // plain store (L2 WB)
          }
          rp[i][r] += __expf(val);
        }
      }
    }
#pragma unroll
    for (int i = 0; i < 4; ++i)
#pragma unroll
      for (int r = 0; r < 4; ++r) {
        float v = rp[i][r];
        v += __shfl_xor(v, 1); v += __shfl_xor(v, 2);
        v += __shfl_xor(v, 4); v += __shfl_xor(v, 8);
        if (l15 == 0) atomicAdd(&rs[mh + i * 16 + quad * 4 + r], v);
      }
    __syncthreads();
    if (tid < 128) {
      int rg = row0 + tid;
      if (rg < MROW_) atomicAdd(&row_sums[rg], rs[tid]);
    }
  }
}

// ---------------------------------------------------------------- k_lsm
__global__ __launch_bounds__(256) void k_lsm(float* __restrict__ out,
                                             const float* __restrict__ row_sums, int n4) {
  int i = blockIdx.x * 256 + threadIdx.x;
  if (i >= n4) return;
  f32x4* o4 = (f32x4*)out;
  f32x4 v = o4[i];
  int r = i / 8000;              // V/4 = 8000 vec4 per row; row = b*63 + t
  int b = r / 63, t = r - b * 63;
  float ls = __logf(row_sums[t * 32 + b]);
  v[0] -= ls; v[1] -= ls; v[2] -= ls; v[3] -= ls;
  o4[i] = v;
}

// ---------------------------------------------------------------- launch
extern "C" void kernel_launch(void* const* d_in, const int* in_sizes, int n_in,
                              void* d_out, int out_size, void* d_ws, size_t ws_size,
                              hipStream_t stream) {
  const int*   target  = (const int*)d_in[0];
  const float* enc_out = (const float*)d_in[1];
  const float* enc_h0  = (const float*)d_in[2];
  const float* enc_c0  = (const float*)d_in[3];
  const float* emb     = (const float*)d_in[4];
  const float* W_x     = (const float*)d_in[5];
  const float* W_h     = (const float*)d_in[6];
  const float* b_lstm  = (const float*)d_in[7];
  const float* Wa      = (const float*)d_in[8];
  const float* W_fc    = (const float*)d_in[9];
  const float* b_fc    = (const float*)d_in[10];
  float* out = (float*)d_out;
  char* ws = (char*)d_ws;

  // ws layout (bytes); total ~84.4 MiB
  unsigned int*   hcnt     = (unsigned int*)(ws + 0);             // 2048 u32
  float*          row_sums = (float*)(ws + 8192);                 // 2016 f32
  unsigned short* fragWh   = (unsigned short*)(ws + 16384);       // 2 MiB
  unsigned int*   hseq32   = (unsigned int*)(ws + 2113536);       // 2 MiB (64 steps)
  unsigned short* Zx       = (unsigned short*)(ws + 4210688);     // 8.25 MB (bf16)
  float*          enc_proj = (float*)(ws + 12468224);             // 4 MiB
  unsigned short* Afc      = (unsigned short*)(ws + 16662528);    // 4 MiB (2048x1024)
  unsigned short* encT     = (unsigned short*)(ws + 20856832);    // 2 MiB (bf16)
  unsigned short* WfcT     = (unsigned short*)(ws + 22953984);    // 62.5 MiB

  unsigned int* AfcFlags = (unsigned int*)(ws + 16662528 + (size_t)AFC_FLAG_U32 * 4);

  // 3 launches: prep (small precompute), rec (recurrence + attention + FC,
  // flag-gated, WfcT transpose in recurrence shadow), lsm (normalize).
  k_prep <<<dim3(1536),         dim3(256), 0, stream>>>(target, emb, W_x, b_lstm,
                                                        enc_out, Wa, W_h,
                                                        fragWh, Zx, enc_proj, encT,
                                                        hcnt, row_sums, AfcFlags);
  k_rec  <<<dim3(64 + NFCX_ * NFCY_), dim3(256), 0, stream>>>(enc_h0, enc_c0,
                                                        enc_proj, Zx, fragWh, encT,
                                                        hseq32, Afc, hcnt,
                                                        WfcT, b_fc, out, row_sums,
                                                        W_fc);
  k_lsm  <<<dim3(63000),        dim3(256), 0, stream>>>(out, row_sums, 16128000);
}

// Round 6
// 961.081 us; speedup vs baseline: 1.3698x; 1.1067x over previous
//
#include <hip/hip_runtime.h>
#include <stdint.h>

// Problem constants (from reference)
#define B_   32
#define T_   63      // S-1
#define U_   512
#define E_   256
#define V_   32000
#define L_   64
#define FU_  2048    // 4U
#define KFC_ 1024    // 2U
#define MROW_ 2016   // B*T

// Roles in k_rec (512-thread blocks):
//   blocks 0..15   : producers (p) — u-slice [p*32, p*32+32) of all 4 gates
//   blocks 16..47  : consumers (b) — attention for batch b
//   blocks 48..2047: FC — TWO 128x128 tiles per block (halves tid>>8)
#define NFCX_ 250    // 32000/128 col panels
#define NFCY_ 16     // 2048/128 row panels
#define CCNT_BASE 1024   // ccnt[t] (consumer counter) at hcnt[CCNT_BASE + t*16]
// h flags: hcnt[t*16 + p] = 1 when producer p published h[t] (16 words = one
// 64B line per t -> pollers fetch all flags in ONE LLC round trip, no RMW).
#define AFC_FLAG_U32 (2016 * 512)   // wfcTrdy[cx] at AfcFlags[cx*16]

typedef float f32x4 __attribute__((ext_vector_type(4)));
typedef __bf16 bf16x8 __attribute__((ext_vector_type(8)));

__device__ __forceinline__ unsigned short f2bf(float f) {
  union { float f; unsigned u; } v; v.f = f;
  unsigned u = v.u;
  u += 0x7FFFu + ((u >> 16) & 1u);   // round-to-nearest-even
  return (unsigned short)(u >> 16);
}
__device__ __forceinline__ float bf2f(unsigned short h) {
  union { unsigned u; float f; } v; v.u = ((unsigned)h) << 16;
  return v.f;
}
__device__ __forceinline__ float fast_sigmoid(float x) {
  return 1.f / (1.f + __expf(-x));
}
__device__ __forceinline__ float fast_tanh(float x) {
  float e = __expf(2.f * x);
  return 1.f - 2.f / (e + 1.f);
}

// ---------------------------------------------------------------- k_prep
__global__ __launch_bounds__(256) void k_prep(const int* __restrict__ target,
    const float* __restrict__ emb, const float* __restrict__ W_x,
    const float* __restrict__ b_lstm, const float* __restrict__ enc_out,
    const float* __restrict__ Wa, const float* __restrict__ W_h,
    unsigned short* __restrict__ fragWh, unsigned short* __restrict__ Zx,
    float* __restrict__ enc_proj, unsigned short* __restrict__ encT,
    unsigned int* __restrict__ hcnt, float* __restrict__ row_sums,
    unsigned int* __restrict__ AfcFlags) {
  __shared__ __align__(16) char smem[32768];
  const int bx = blockIdx.x;
  const int tid = threadIdx.x;

  if (bx < 512) {
    // ---- fragWh[ct][kc][lane][j] = bf16(W_h[kc*32+(lane>>4)*8+j][ct*16+(lane&15)])
    int idx = bx * 256 + tid;   // 0..131071
    int lane = idx & 63;
    int kc   = (idx >> 6) & 15;
    int ct   = idx >> 10;
    int quad = lane >> 4, l15 = lane & 15;
    int col = ct * 16 + l15;
    unsigned short* dst = fragWh + (size_t)idx * 8;
#pragma unroll
    for (int j = 0; j < 8; ++j) {
      int k = kc * 32 + quad * 8 + j;
      dst[j] = f2bf(W_h[(size_t)k * FU_ + col]);
    }
  } else if (bx < 1016) {
    // ---- Zx
    float* x_lds = (float*)smem;          // 32 KB
    int r = bx - 512;                     // 0..503
    int t = r % 63, cc = r / 63;
    for (int i = tid; i < B_ * E_; i += 256) {
      int b = i >> 8, e = i & 255;
      x_lds[i] = emb[(size_t)target[b * 64 + t] * E_ + e];
    }
    __syncthreads();
    int col = cc * 256 + tid;
    float acc[B_];
#pragma unroll
    for (int b = 0; b < B_; ++b) acc[b] = 0.f;
    for (int e4 = 0; e4 < E_ / 4; ++e4) {
      float w0 = W_x[(size_t)(4 * e4 + 0) * FU_ + col];
      float w1 = W_x[(size_t)(4 * e4 + 1) * FU_ + col];
      float w2 = W_x[(size_t)(4 * e4 + 2) * FU_ + col];
      float w3 = W_x[(size_t)(4 * e4 + 3) * FU_ + col];
#pragma unroll
      for (int b = 0; b < B_; ++b) {
        f32x4 xv = *(const f32x4*)&x_lds[b * E_ + 4 * e4];
        acc[b] += xv[0] * w0 + xv[1] * w1 + xv[2] * w2 + xv[3] * w3;
      }
    }
    float bias = b_lstm[col];
#pragma unroll
    for (int b = 0; b < B_; ++b)
      Zx[((size_t)(t * B_ + b)) * FU_ + col] = f2bf(acc[b] + bias);
  } else if (bx < 1272) {
    // ---- enc_proj
    float* e_lds = (float*)smem;          // 32 KB
    int r = bx - 1016;                    // 0..255
    int rc = r & 127, cc = r >> 7;
    int row0 = rc * 16;
    for (int i = tid; i < 16 * U_; i += 256)
      e_lds[i] = enc_out[(size_t)(row0 + (i >> 9)) * U_ + (i & 511)];
    __syncthreads();
    int col = cc * 256 + tid;
    float acc[16];
#pragma unroll
    for (int q = 0; q < 16; ++q) acc[q] = 0.f;
    for (int k4 = 0; k4 < U_ / 4; ++k4) {
      float w0 = Wa[(size_t)(4 * k4 + 0) * U_ + col];
      float w1 = Wa[(size_t)(4 * k4 + 1) * U_ + col];
      float w2 = Wa[(size_t)(4 * k4 + 2) * U_ + col];
      float w3 = Wa[(size_t)(4 * k4 + 3) * U_ + col];
#pragma unroll
      for (int q = 0; q < 16; ++q) {
        f32x4 xv = *(const f32x4*)&e_lds[q * U_ + 4 * k4];
        acc[q] += xv[0] * w0 + xv[1] * w1 + xv[2] * w2 + xv[3] * w3;
      }
    }
#pragma unroll
    for (int q = 0; q < 16; ++q)
      enc_proj[(size_t)(row0 + q) * U_ + col] = acc[q];
  } else if (bx < 1528) {
    // ---- encT[b][u][l] = bf16(enc_out[b][l][u])
    float (*tile)[65] = (float(*)[65])smem;   // 64x65 f32
    int r = bx - 1272;                        // 0..255
    int b = r & 31, uc = r >> 5;
#pragma unroll
    for (int i = 0; i < 16; ++i) {
      int idx = i * 256 + tid;            // 0..4095
      int l = idx >> 6, u = idx & 63;
      tile[l][u] = enc_out[((size_t)b * L_ + l) * U_ + uc * 64 + u];
    }
    __syncthreads();
#pragma unroll
    for (int i = 0; i < 16; ++i) {
      int idx = i * 256 + tid;
      int u = idx >> 6, l = idx & 63;
      encT[((size_t)b * U_ + uc * 64 + u) * L_ + l] = f2bf(tile[l][u]);
    }
  } else {
    // ---- zero flags (hcnt + ccnt) + Afc flag region + row_sums
    int i = (bx - 1528) * 256 + tid;      // 0..2047
    hcnt[i] = 0u;
    if (i < MROW_) row_sums[i] = 0.f;
    AfcFlags[i * 4 + 0] = 0u;
    AfcFlags[i * 4 + 1] = 0u;
    AfcFlags[i * 4 + 2] = 0u;
    AfcFlags[i * 4 + 3] = 0u;
  }
}

// ---------------------------------------------------------------- k_rec
// 2048 blocks x 512 threads.
// Exchange protocol: producers publish h-slices (agent atomic stores) ->
// __syncthreads drains vmcnt(0) -> tid0 stores 1 to hcnt[(t+1)*16+p] (plain
// store, NO RMW). Pollers read the whole 16-flag line in one load + __all.
__global__ __launch_bounds__(512, 2) void k_rec(const float* __restrict__ enc_h0,
    const float* __restrict__ enc_c0,
    const float* __restrict__ enc_proj, const unsigned short* __restrict__ Zx,
    const unsigned short* __restrict__ fragWh, const unsigned short* __restrict__ encT,
    unsigned int* hseq32,                  // 64 steps x 8192 u32 (bf16 pairs)
    unsigned short* __restrict__ Afc,      // 2048 x 1024 bf16 [ctx | h] + flag rows
    unsigned int* hcnt,
    unsigned short* __restrict__ WfcT, const float* __restrict__ b_fc,
    float* __restrict__ out, float* __restrict__ row_sums,
    const float* __restrict__ W_fc) {
  // LDS union: producer 54528 B | consumer ~4.5 KB | fc 2x17408 B
  __shared__ __align__(16) char smem[54528];

  const int tid = threadIdx.x;
  unsigned long long* hseq64 = (unsigned long long*)hseq32;
  unsigned int* AfcFlags = (unsigned int*)Afc + AFC_FLAG_U32;

  if (blockIdx.x < 16) {
    // ---------------- producer p: slices g = 2p, 2p+1 (u in [32p, 32p+32))
    unsigned short* h_lds = (unsigned short*)smem;        // 32 x 520 u16 = 33280 B
    float* z_lds = (float*)(smem + 33280);                // 32 x 132 f32 = 16896 B
    float* c_lds = (float*)(smem + 50176);                // 32 x 34 f32 = 4352 B

    const int p = blockIdx.x;
    const int ww = tid >> 6;           // wave 0..7
    const int w = ww & 3;              // gate
    const int hf = ww >> 2;            // row half (b 0..15 / 16..31)
    const int lane = tid & 63;
    const int quad = lane >> 4;
    const int l15 = lane & 15;
    const int b = tid >> 4;            // gates mapping: 32 b x 16 j
    const int j = tid & 15;            // u = 32p + 2j, 2j+1

    // step-invariant W_h B-fragments: 2 slices x 16 kc (128 VGPRs)
    bf16x8 bfr[2][16];
#pragma unroll
    for (int s = 0; s < 2; ++s) {
      const unsigned short* bbase = fragWh + ((size_t)(w * 32 + 2 * p + s) * 16) * 512;
#pragma unroll
      for (int kc = 0; kc < 16; ++kc)
        bfr[s][kc] = *(const bf16x8*)(bbase + (size_t)(kc * 64 + lane) * 8);
    }

    __builtin_amdgcn_s_setprio(1);

    // init: c slice -> LDS; h0 slice -> hseq[0]
    {
      int u = 32 * p + 2 * j;
      float h0a = enc_h0[(size_t)b * U_ + u];
      float h0b = enc_h0[(size_t)b * U_ + u + 1];
      unsigned pack = (unsigned)f2bf(h0a) | ((unsigned)f2bf(h0b) << 16);
      __hip_atomic_store(&hseq32[b * 256 + 16 * p + j], pack,
                         __ATOMIC_RELAXED, __HIP_MEMORY_SCOPE_AGENT);
      c_lds[b * 34 + 2 * j]     = enc_c0[(size_t)b * U_ + u];
      c_lds[b * 34 + 2 * j + 1] = enc_c0[(size_t)b * U_ + u + 1];
    }
    __syncthreads();   // drains vmcnt(0): h0 stores at LLC
    if (tid == 0)
      __hip_atomic_store(&hcnt[p], 1u, __ATOMIC_RELAXED, __HIP_MEMORY_SCOPE_AGENT);

    for (int t = 0; t < T_; ++t) {
      // Zx prefetch (independent of flags)
      const unsigned short* zxbase = Zx + ((size_t)(t * B_ + b)) * FU_ + 32 * p + 2 * j;
      unsigned zxp0 = *(const unsigned*)(zxbase + 0 * U_);
      unsigned zxp1 = *(const unsigned*)(zxbase + 1 * U_);
      unsigned zxp2 = *(const unsigned*)(zxbase + 2 * U_);
      unsigned zxp3 = *(const unsigned*)(zxbase + 3 * U_);

      // wait for all 16 h[t] flags (one 64B line, one load per poll)
      if (tid < 64) {
        int pl = tid & 15;
        while (true) {
          unsigned v = __hip_atomic_load(&hcnt[t * 16 + pl], __ATOMIC_RELAXED,
                                         __HIP_MEMORY_SCOPE_AGENT);
          if (__all(v != 0u)) break;
          __builtin_amdgcn_s_sleep(1);
        }
      }
      __syncthreads();

      // stage h[t] 32KB LLC->LDS (batched: 8 loads then 8 ds_writes)
      const unsigned long long* hp = hseq64 + (size_t)t * 4096;
      unsigned long long hv[8];
#pragma unroll
      for (int i = 0; i < 8; ++i)
        hv[i] = __hip_atomic_load(&hp[i * 512 + tid], __ATOMIC_RELAXED,
                                  __HIP_MEMORY_SCOPE_AGENT);
#pragma unroll
      for (int i = 0; i < 8; ++i) {
        int idx = i * 512 + tid;            // 0..4095
        int hb = idx >> 7, u0 = (idx & 127) * 4;
        *(unsigned long long*)&h_lds[hb * 520 + u0] = hv[i];
      }
      __syncthreads();

      // z-slices: wave (w,hf) computes gate w, rows hf*16..+16, 2 slices
      f32x4 acc0 = {0.f, 0.f, 0.f, 0.f}, acc1 = {0.f, 0.f, 0.f, 0.f};
#pragma unroll
      for (int kc = 0; kc < 16; ++kc) {
        bf16x8 av = *(const bf16x8*)&h_lds[(hf * 16 + l15) * 520 + kc * 32 + quad * 8];
        acc0 = __builtin_amdgcn_mfma_f32_16x16x32_bf16(av, bfr[0][kc], acc0, 0, 0, 0);
        acc1 = __builtin_amdgcn_mfma_f32_16x16x32_bf16(av, bfr[1][kc], acc1, 0, 0, 0);
      }
#pragma unroll
      for (int r = 0; r < 4; ++r) {
        z_lds[(hf * 16 + quad * 4 + r) * 132 + w * 32 + l15]      = acc0[r];
        z_lds[(hf * 16 + quad * 4 + r) * 132 + w * 32 + 16 + l15] = acc1[r];
      }
      __syncthreads();

      // gates + state update for (b, 2j) and (b, 2j+1); u_local = 2j
      {
        int up0 = 2 * j, up1 = 2 * j + 1;
        const float* zb = z_lds + b * 132;
        float zi0 = zb[ 0 + up0] + bf2f((unsigned short)(zxp0 & 0xFFFFu));
        float zi1 = zb[ 0 + up1] + bf2f((unsigned short)(zxp0 >> 16));
        float zf0 = zb[32 + up0] + bf2f((unsigned short)(zxp1 & 0xFFFFu));
        float zf1 = zb[32 + up1] + bf2f((unsigned short)(zxp1 >> 16));
        float zg0 = zb[64 + up0] + bf2f((unsigned short)(zxp2 & 0xFFFFu));
        float zg1 = zb[64 + up1] + bf2f((unsigned short)(zxp2 >> 16));
        float zo0 = zb[96 + up0] + bf2f((unsigned short)(zxp3 & 0xFFFFu));
        float zo1 = zb[96 + up1] + bf2f((unsigned short)(zxp3 >> 16));
        float i0 = fast_sigmoid(zi0), i1 = fast_sigmoid(zi1);
        float f0 = fast_sigmoid(zf0), f1 = fast_sigmoid(zf1);
        float g0 = fast_tanh(zg0),    g1 = fast_tanh(zg1);
        float o0 = fast_sigmoid(zo0), o1 = fast_sigmoid(zo1);
        float c0 = f0 * c_lds[b * 34 + up0] + i0 * g0;
        float c1 = f1 * c_lds[b * 34 + up1] + i1 * g1;
        c_lds[b * 34 + up0] = c0;
        c_lds[b * 34 + up1] = c1;
        float h0 = o0 * fast_tanh(c0);
        float h1 = o1 * fast_tanh(c1);
        unsigned pack = (unsigned)f2bf(h0) | ((unsigned)f2bf(h1) << 16);
        __hip_atomic_store(&hseq32[(size_t)(t + 1) * 8192 + b * 256 + 16 * p + j],
                           pack, __ATOMIC_RELAXED, __HIP_MEMORY_SCOPE_AGENT);
        __hip_atomic_store(
            (unsigned*)&Afc[(size_t)(t * B_ + b) * KFC_ + U_ + 32 * p + 2 * j],
            pack, __ATOMIC_RELAXED, __HIP_MEMORY_SCOPE_AGENT);
      }
      __syncthreads();   // drains vmcnt(0): publish stores at LLC
      if (tid == 0)
        __hip_atomic_store(&hcnt[(t + 1) * 16 + p], 1u,
                           __ATOMIC_RELAXED, __HIP_MEMORY_SCOPE_AGENT);
    }
  } else if (blockIdx.x < 48) {
    // ---------------- consumer: attention for batch b ----------------
    float* h_sh    = (float*)smem;            // 512 f32 = 2048 B
    float* sc_part = (float*)(smem + 2048);   // 512 f32 = 2048 B
    float* probs   = (float*)(smem + 4096);   // 64 f32  = 256 B

    __builtin_amdgcn_s_setprio(1);
    const int b = blockIdx.x - 16;
    for (int t = 0; t < T_; ++t) {
      if (tid < 64) {
        int pl = tid & 15;
        while (true) {
          unsigned v = __hip_atomic_load(&hcnt[(t + 1) * 16 + pl], __ATOMIC_RELAXED,
                                         __HIP_MEMORY_SCOPE_AGENT);
          if (__all(v != 0u)) break;
          __builtin_amdgcn_s_sleep(2);
        }
      }
      __syncthreads();
      // read h[t+1][b] (512 bf16 = 128 u64)
      if (tid < 128) {
        unsigned long long v = __hip_atomic_load(
            &hseq64[(size_t)(t + 1) * 4096 + b * 128 + tid],
            __ATOMIC_RELAXED, __HIP_MEMORY_SCOPE_AGENT);
        int u0 = tid * 4;
        h_sh[u0 + 0] = bf2f((unsigned short)(v & 0xFFFFu));
        h_sh[u0 + 1] = bf2f((unsigned short)((v >> 16) & 0xFFFFu));
        h_sh[u0 + 2] = bf2f((unsigned short)((v >> 32) & 0xFFFFu));
        h_sh[u0 + 3] = bf2f((unsigned short)((v >> 48) & 0xFFFFu));
      }
      __syncthreads();
      // score[l] = h . enc_proj[b,l,:]  (8 parts x 64 l)
      {
        int l = tid & 63, part = tid >> 6;
        const float* ep = enc_proj + ((size_t)(b * L_ + l)) * U_ + part * 64;
        const float* hs = h_sh + part * 64;
        float s = 0.f;
#pragma unroll
        for (int u = 0; u < 64; u += 4) {
          f32x4 e = *(const f32x4*)(ep + u);
          s += hs[u] * e[0] + hs[u + 1] * e[1] + hs[u + 2] * e[2] + hs[u + 3] * e[3];
        }
        sc_part[part * 64 + l] = s;
      }
      __syncthreads();
      if (tid < 64) {
        float s = 0.f;
#pragma unroll
        for (int q = 0; q < 8; ++q) s += sc_part[q * 64 + tid];
        float m = s;
#pragma unroll
        for (int off = 32; off >= 1; off >>= 1) m = fmaxf(m, __shfl_xor(m, off));
        float e = __expf(s - m);
        float sum = e;
#pragma unroll
        for (int off = 32; off >= 1; off >>= 1) sum += __shfl_xor(sum, off);
        probs[tid] = e / sum;
      }
      __syncthreads();
      // ctx: one u per thread; pack pairs via shfl
      {
        int u = tid;
        const unsigned short* ep0 = encT + ((size_t)b * U_ + u) * L_;
        float c0 = 0.f;
#pragma unroll
        for (int l8 = 0; l8 < 8; ++l8) {
          bf16x8 e0 = *(const bf16x8*)(ep0 + l8 * 8);
#pragma unroll
          for (int q = 0; q < 8; ++q) c0 += probs[l8 * 8 + q] * (float)e0[q];
        }
        float c1 = __shfl_xor(c0, 1);
        if ((tid & 1) == 0) {
          unsigned pack = (unsigned)f2bf(c0) | ((unsigned)f2bf(c1) << 16);
          __hip_atomic_store((unsigned*)&Afc[(size_t)(t * B_ + b) * KFC_ + u], pack,
                             __ATOMIC_RELAXED, __HIP_MEMORY_SCOPE_AGENT);
        }
      }
      __syncthreads();   // drains vmcnt(0): ctx stores at LLC
      if (tid == 0)
        __hip_atomic_fetch_add(&hcnt[CCNT_BASE + t * 16], 1u,
                               __ATOMIC_RELAXED, __HIP_MEMORY_SCOPE_AGENT);
    }
  } else {
    // ---------------- folded FC: two 128x128 tiles per block ----------------
    const int t2 = tid & 255;          // thread within half
    const int half = tid >> 8;         // 0 or 1
    char* sm = smem + half * 17408;
    unsigned short* At = (unsigned short*)sm;           // 8192 B
    unsigned short* Bt = (unsigned short*)(sm + 8192);  // 8192 B
    float* rs = (float*)(sm + 16384);                   // 512 B

    const int fcid = blockIdx.x - 48;      // 0..1999
    const int ti = fcid * 2 + half;        // tile 0..3999, ry-major
    const int cx = ti % NFCX_, ry = ti / NFCX_;
    int t_hi = 4 * ry + 3; if (t_hi > T_ - 1) t_hi = T_ - 1;

    if (fcid < 125) {
      // both halves have ry==0 (250 = 125*2): transpose W_fc panel cx
      float* tile = (float*)sm;            // 32 x 132 f32 = 16896 B
      const int n0 = cx * 128;
      for (int kt2 = 0; kt2 < 32; ++kt2) {
        int k0 = kt2 * 32;
#pragma unroll
        for (int it = 0; it < 4; ++it) {
          int lin = it * 256 + t2;         // 0..1023
          int k = lin >> 5, nq = lin & 31;
          f32x4 v = *(const f32x4*)(W_fc + (size_t)(k0 + k) * V_ + n0 + nq * 4);
          *(f32x4*)&tile[k * 132 + nq * 4] = v;
        }
        __syncthreads();
#pragma unroll
        for (int it = 0; it < 4; ++it) {
          int lin = it * 256 + t2;
          int n = lin >> 3, kq = lin & 7;
          float a0 = tile[(kq * 4 + 0) * 132 + n];
          float a1 = tile[(kq * 4 + 1) * 132 + n];
          float a2 = tile[(kq * 4 + 2) * 132 + n];
          float a3 = tile[(kq * 4 + 3) * 132 + n];
          unsigned long long pk =
              (unsigned long long)((unsigned)f2bf(a0) | ((unsigned)f2bf(a1) << 16)) |
              ((unsigned long long)((unsigned)f2bf(a2) | ((unsigned)f2bf(a3) << 16)) << 32);
          __hip_atomic_store(
              (unsigned long long*)&WfcT[(size_t)(n0 + n) * KFC_ + k0 + kq * 4], pk,
              __ATOMIC_RELAXED, __HIP_MEMORY_SCOPE_AGENT);
        }
        __syncthreads();   // drains vmcnt for this tile's stores
      }
      if (t2 == 0)
        __hip_atomic_store(&AfcFlags[cx * 16], 1u,
                           __ATOMIC_RELAXED, __HIP_MEMORY_SCOPE_AGENT);
    }

    // wait: B-panel ready (ry>0) AND consumer step t_hi complete (per half)
    if (t2 == 0) {
      if (ry != 0) {
        while (__hip_atomic_load(&AfcFlags[cx * 16], __ATOMIC_RELAXED,
                                 __HIP_MEMORY_SCOPE_AGENT) == 0u)
          __builtin_amdgcn_s_sleep(16);
      }
      while (__hip_atomic_load(&hcnt[CCNT_BASE + t_hi * 16], __ATOMIC_RELAXED,
                               __HIP_MEMORY_SCOPE_AGENT) < 32u)
        __builtin_amdgcn_s_sleep(32);
    }
    __syncthreads();

    const int w = t2 >> 6, lane = t2 & 63, quad = lane >> 4, l15 = lane & 15;
    const int row0 = ry * 128, col0 = cx * 128;
    const int mh = (w >> 1) * 64, nh = (w & 1) * 64;

    f32x4 acc[4][4];
#pragma unroll
    for (int i = 0; i < 4; ++i)
#pragma unroll
      for (int jj = 0; jj < 4; ++jj) { f32x4 z = {0.f, 0.f, 0.f, 0.f}; acc[i][jj] = z; }

    for (int kt = 0; kt < KFC_ / 32; ++kt) {
      int k0 = kt * 32;
#pragma unroll
      for (int i = 0; i < 2; ++i) {
        int lin = i * 256 + t2;
        int r = lin >> 2, s = lin & 3;
        int gseg = (s - (r >> 1)) & 3;     // XOR swizzle
        f32x4 va = *(const f32x4*)(Afc + ((size_t)(row0 + r)) * KFC_ + k0 + gseg * 8);
        *(f32x4*)&At[r * 32 + s * 8] = va;
        f32x4 vb = *(const f32x4*)(WfcT + ((size_t)(col0 + r)) * KFC_ + k0 + gseg * 8);
        *(f32x4*)&Bt[r * 32 + s * 8] = vb;
      }
      __syncthreads();
      bf16x8 a[4], b[4];
#pragma unroll
      for (int i = 0; i < 4; ++i) {
        int m = mh + i * 16 + l15;
        a[i] = *(const bf16x8*)&At[m * 32 + (((quad + (m >> 1)) & 3) * 8)];
        int n = nh + i * 16 + l15;
        b[i] = *(const bf16x8*)&Bt[n * 32 + (((quad + (n >> 1)) & 3) * 8)];
      }
#pragma unroll
      for (int i = 0; i < 4; ++i)
#pragma unroll
        for (int jj = 0; jj < 4; ++jj)
          acc[i][jj] = __builtin_amdgcn_mfma_f32_16x16x32_bf16(a[i], b[jj], acc[i][jj], 0, 0, 0);
      __syncthreads();
    }

    if (t2 < 128) rs[t2] = 0.f;
    __syncthreads();
    float bv[4];
#pragma unroll
    for (int jj = 0; jj < 4; ++jj) bv[jj] = b_fc[col0 + nh + jj * 16 + l15];
    float rp[4][4];
#pragma unroll
    for (int i = 0; i < 4; ++i)
#pragma unroll
      for (int r = 0; r < 4; ++r) rp[i][r] = 0.f;
#pragma unroll
    for (int i = 0; i < 4; ++i) {
#pragma unroll
      for (int jj = 0; jj < 4; ++jj) {
        int cg = col0 + nh + jj * 16 + l15;
#pragma unroll
        for (int r = 0; r < 4; ++r) {
          float val = fast_tanh(acc[i][jj][r] + bv[jj]);
          int rg = row0 + mh + i * 16 + quad * 4 + r;
          if (rg < MROW_) {
            int b = rg & 31, t = rg >> 5;
            out[((size_t)(b * T_ + t)) * V_ + cg] = val;   // plain store (L2 WB)
          }
          rp[i][r] += __expf(val);
        }
      }
    }
#pragma unroll
    for (int i = 0; i < 4; ++i)
#pragma unroll
      for (int r = 0; r < 4; ++r) {
        float v = rp[i][r];
        v += __shfl_xor(v, 1); v += __shfl_xor(v, 2);
        v += __shfl_xor(v, 4); v += __shfl_xor(v, 8);
        if (l15 == 0) atomicAdd(&rs[mh + i * 16 + quad * 4 + r], v);
      }
    __syncthreads();
    if (t2 < 128) {
      int rg = row0 + t2;
      if (rg < MROW_) atomicAdd(&row_sums[rg], rs[t2]);
    }
  }
}

// ---------------------------------------------------------------- k_lsm
__global__ __launch_bounds__(256) void k_lsm(float* __restrict__ out,
                                             const float* __restrict__ row_sums, int n4) {
  int i = blockIdx.x * 256 + threadIdx.x;
  if (i >= n4) return;
  f32x4* o4 = (f32x4*)out;
  f32x4 v = o4[i];
  int r = i / 8000;              // V/4 = 8000 vec4 per row; row = b*63 + t
  int b = r / 63, t = r - b * 63;
  float ls = __logf(row_sums[t * 32 + b]);
  v[0] -= ls; v[1] -= ls; v[2] -= ls; v[3] -= ls;
  o4[i] = v;
}

// ---------------------------------------------------------------- launch
extern "C" void kernel_launch(void* const* d_in, const int* in_sizes, int n_in,
                              void* d_out, int out_size, void* d_ws, size_t ws_size,
                              hipStream_t stream) {
  const int*   target  = (const int*)d_in[0];
  const float* enc_out = (const float*)d_in[1];
  const float* enc_h0  = (const float*)d_in[2];
  const float* enc_c0  = (const float*)d_in[3];
  const float* emb     = (const float*)d_in[4];
  const float* W_x     = (const float*)d_in[5];
  const float* W_h     = (const float*)d_in[6];
  const float* b_lstm  = (const float*)d_in[7];
  const float* Wa      = (const float*)d_in[8];
  const float* W_fc    = (const float*)d_in[9];
  const float* b_fc    = (const float*)d_in[10];
  float* out = (float*)d_out;
  char* ws = (char*)d_ws;

  // ws layout (bytes); total ~84.4 MiB
  unsigned int*   hcnt     = (unsigned int*)(ws + 0);             // 2048 u32
  float*          row_sums = (float*)(ws + 8192);                 // 2016 f32
  unsigned short* fragWh   = (unsigned short*)(ws + 16384);       // 2 MiB
  unsigned int*   hseq32   = (unsigned int*)(ws + 2113536);       // 2 MiB (64 steps)
  unsigned short* Zx       = (unsigned short*)(ws + 4210688);     // 8.25 MB (bf16)
  float*          enc_proj = (float*)(ws + 12468224);             // 4 MiB
  unsigned short* Afc      = (unsigned short*)(ws + 16662528);    // 4 MiB (2048x1024)
  unsigned short* encT     = (unsigned short*)(ws + 20856832);    // 2 MiB (bf16)
  unsigned short* WfcT     = (unsigned short*)(ws + 22953984);    // 62.5 MiB

  unsigned int* AfcFlags = (unsigned int*)(ws + 16662528 + (size_t)AFC_FLAG_U32 * 4);

  k_prep <<<dim3(1536),  dim3(256), 0, stream>>>(target, emb, W_x, b_lstm,
                                                 enc_out, Wa, W_h,
                                                 fragWh, Zx, enc_proj, encT,
                                                 hcnt, row_sums, AfcFlags);
  k_rec  <<<dim3(2048),  dim3(512), 0, stream>>>(enc_h0, enc_c0,
                                                 enc_proj, Zx, fragWh, encT,
                                                 hseq32, Afc, hcnt,
                                                 WfcT, b_fc, out, row_sums,
                                                 W_fc);
  k_lsm  <<<dim3(63000), dim3(256), 0, stream>>>(out, row_sums, 16128000);
}